// Round 1
// baseline (642.553 us; speedup 1.0000x reference)
//
#include <hip/hip_runtime.h>
#include <hip/hip_runtime_api.h>
#include <math.h>

// CrossLocal: B=4, C=64, CI=32, cross 64x64 (Nc=4096), main 128x128.
// ws layout (floats): Q[16384*32] K[...] V[...] O[...] out2[4*64*4096] stats[128]

// ---------------- Kernel 1: Q,K,V prep ----------------
// Q = g(cross), K = theta(cross), V = phi(avgpool2x2(main))
__global__ __launch_bounds__(64) void qkv_kernel(
    const float* __restrict__ cross, const float* __restrict__ mainf,
    const float* __restrict__ g_w,  const float* __restrict__ g_b,
    const float* __restrict__ th_w, const float* __restrict__ th_b,
    const float* __restrict__ ph_w, const float* __restrict__ ph_b,
    float* __restrict__ Q, float* __restrict__ K, float* __restrict__ V)
{
    int pix = blockIdx.x * 64 + threadIdx.x;   // 0..16383
    int b = pix >> 12, n = pix & 4095;
    int i = n >> 6, j = n & 63;

    float aq[32], ak[32], av[32];
#pragma unroll
    for (int ci = 0; ci < 32; ++ci) { aq[ci] = g_b[ci]; ak[ci] = th_b[ci]; av[ci] = ph_b[ci]; }

    const float* cp = cross + (size_t)(b * 64) * 4096 + n;
    const float* mp = mainf + (size_t)(b * 64) * 16384 + i * 256 + j * 2;
    for (int c = 0; c < 64; ++c) {
        float xc = cp[(size_t)c * 4096];
        const float* m = mp + (size_t)c * 16384;
        // bilinear 128->64 with align_corners=False == 2x2 average pool
        float xm = 0.25f * (m[0] + m[1] + m[128] + m[129]);
#pragma unroll
        for (int ci = 0; ci < 32; ++ci) {
            aq[ci] = fmaf(g_w [(ci << 6) + c], xc, aq[ci]);
            ak[ci] = fmaf(th_w[(ci << 6) + c], xc, ak[ci]);
            av[ci] = fmaf(ph_w[(ci << 6) + c], xm, av[ci]);
        }
    }
    float4* Qp = (float4*)(Q + (size_t)pix * 32);
    float4* Kp = (float4*)(K + (size_t)pix * 32);
    float4* Vp = (float4*)(V + (size_t)pix * 32);
#pragma unroll
    for (int r = 0; r < 8; ++r) {
        Qp[r] = make_float4(aq[4*r], aq[4*r+1], aq[4*r+2], aq[4*r+3]);
        Kp[r] = make_float4(ak[4*r], ak[4*r+1], ak[4*r+2], ak[4*r+3]);
        Vp[r] = make_float4(av[4*r], av[4*r+1], av[4*r+2], av[4*r+3]);
    }
}

// ---------------- Kernel 2: attention ----------------
// grid (64 qtiles, 4 batch) x 256 threads. lane = query within tile,
// wave w owns keys [w*1024, w*1024+1024). Logits are bounded (~|x|<10) so
// exp-sum without max subtraction is safe in fp32 -> purely additive partials.
__global__ __launch_bounds__(256) void attn_kernel(
    const float* __restrict__ Q, const float* __restrict__ K,
    const float* __restrict__ V, float* __restrict__ O)
{
    __shared__ float lds[4 * 2048];     // per-wave 8KB region: K chunk (1024 f) + V chunk (1024 f)
    __shared__ float ldsden[3 * 64];
    const int tid  = threadIdx.x;
    const int lane = tid & 63;
    const int w    = tid >> 6;
    const int b    = blockIdx.y;
    const int qidx = (blockIdx.x << 6) | lane;

    float qr[32];
    {
        const float4* Qp = (const float4*)(Q + ((size_t)(b << 12) + qidx) * 32);
#pragma unroll
        for (int r = 0; r < 8; ++r) {
            float4 v4 = Qp[r];
            qr[4*r] = v4.x; qr[4*r+1] = v4.y; qr[4*r+2] = v4.z; qr[4*r+3] = v4.w;
        }
    }
    float num[32];
#pragma unroll
    for (int r = 0; r < 32; ++r) num[r] = 0.0f;
    float den = 0.0f;

    float* myK = lds + (w << 11);
    float* myV = myK + 1024;
    const float* Kb = K + (size_t)(b << 12) * 32;
    const float* Vb = V + (size_t)(b << 12) * 32;

    for (int ch = 0; ch < 32; ++ch) {
        const int k0 = (w << 10) + (ch << 5);   // 32 keys per chunk
        const float4* gK = (const float4*)(Kb + (size_t)k0 * 32);
        const float4* gV = (const float4*)(Vb + (size_t)k0 * 32);
#pragma unroll
        for (int r = 0; r < 4; ++r) {
            ((float4*)myK)[(r << 6) | lane] = gK[(r << 6) | lane];
            ((float4*)myV)[(r << 6) | lane] = gV[(r << 6) | lane];
        }
        // same-wave LDS RAW: compiler inserts lgkmcnt waits; regions are per-wave
#pragma unroll 4
        for (int kk = 0; kk < 32; ++kk) {
            const float4* kr = (const float4*)(myK + (kk << 5));
            float d0 = 0.f, d1 = 0.f;
#pragma unroll
            for (int r = 0; r < 8; r += 2) {
                float4 a  = kr[r];
                float4 c4 = kr[r + 1];
                d0 = fmaf(a.x,  qr[4*r],   d0);
                d0 = fmaf(a.y,  qr[4*r+1], d0);
                d0 = fmaf(a.z,  qr[4*r+2], d0);
                d0 = fmaf(a.w,  qr[4*r+3], d0);
                d1 = fmaf(c4.x, qr[4*r+4], d1);
                d1 = fmaf(c4.y, qr[4*r+5], d1);
                d1 = fmaf(c4.z, qr[4*r+6], d1);
                d1 = fmaf(c4.w, qr[4*r+7], d1);
            }
            float p = __expf(d0 + d1);
            den += p;
            const float4* vr = (const float4*)(myV + (kk << 5));
#pragma unroll
            for (int r = 0; r < 8; ++r) {
                float4 v4 = vr[r];
                num[4*r]   = fmaf(p, v4.x, num[4*r]);
                num[4*r+1] = fmaf(p, v4.y, num[4*r+1]);
                num[4*r+2] = fmaf(p, v4.z, num[4*r+2]);
                num[4*r+3] = fmaf(p, v4.w, num[4*r+3]);
            }
        }
    }

    // cross-wave reduction: waves 1..3 dump partials into their own (now dead)
    // staging regions; wave 0 combines and writes O = num/den.
    if (w != 0) {
        float* dst = lds + (w << 11);
#pragma unroll
        for (int r = 0; r < 8; ++r)
            ((float4*)dst)[(r << 6) | lane] =
                make_float4(num[4*r], num[4*r+1], num[4*r+2], num[4*r+3]);
        ldsden[((w - 1) << 6) | lane] = den;
    }
    __syncthreads();
    if (w == 0) {
#pragma unroll
        for (int ww = 1; ww < 4; ++ww) {
            const float4* src = (const float4*)(lds + (ww << 11));
#pragma unroll
            for (int r = 0; r < 8; ++r) {
                float4 v4 = src[(r << 6) | lane];
                num[4*r]   += v4.x; num[4*r+1] += v4.y;
                num[4*r+2] += v4.z; num[4*r+3] += v4.w;
            }
            den += ldsden[((ww - 1) << 6) | lane];
        }
        float inv = 1.0f / den;
        float4* Op = (float4*)(O + ((size_t)(b << 12) + qidx) * 32);
#pragma unroll
        for (int r = 0; r < 8; ++r)
            Op[r] = make_float4(num[4*r]*inv, num[4*r+1]*inv,
                                num[4*r+2]*inv, num[4*r+3]*inv);
    }
}

// ---------------- Kernel 3a: W 1x1 conv ----------------
__global__ __launch_bounds__(256) void wconv_kernel(
    const float* __restrict__ O, const float* __restrict__ w_w,
    const float* __restrict__ w_b, float* __restrict__ out2)
{
    int pix = blockIdx.x * 256 + threadIdx.x;   // 0..16383
    int b = pix >> 12, n = pix & 4095;
    float o[32];
    const float4* Op = (const float4*)(O + (size_t)pix * 32);
#pragma unroll
    for (int r = 0; r < 8; ++r) {
        float4 v4 = Op[r];
        o[4*r] = v4.x; o[4*r+1] = v4.y; o[4*r+2] = v4.z; o[4*r+3] = v4.w;
    }
    float* dst = out2 + ((size_t)(b << 6) << 12) + n;
#pragma unroll 4
    for (int co = 0; co < 64; ++co) {
        float acc = w_b[co];
#pragma unroll
        for (int ci = 0; ci < 32; ++ci)
            acc = fmaf(w_w[(co << 5) + ci], o[ci], acc);
        dst[(size_t)co << 12] = acc;
    }
}

// ---------------- Kernel 3b: BN batch statistics ----------------
// one block per channel; plain writes (no atomics -> no ws zero-init needed)
__global__ __launch_bounds__(256) void stats_kernel(
    const float* __restrict__ out2, float* __restrict__ stats)
{
    int co = blockIdx.x, t = threadIdx.x;
    float s = 0.f, s2 = 0.f;
    for (int b = 0; b < 4; ++b) {
        const float* p = out2 + ((size_t)((b << 6) | co) << 12);
#pragma unroll
        for (int ii = 0; ii < 16; ++ii) {
            float v = p[(ii << 8) | t];
            s += v; s2 = fmaf(v, v, s2);
        }
    }
    __shared__ float rs[256], rs2[256];
    rs[t] = s; rs2[t] = s2;
    __syncthreads();
    for (int off = 128; off > 0; off >>= 1) {
        if (t < off) { rs[t] += rs[t + off]; rs2[t] += rs2[t + off]; }
        __syncthreads();
    }
    if (t == 0) { stats[co] = rs[0]; stats[64 + co] = rs2[0]; }
}

// ---------------- Kernel 4: BN + bilinear 64->128 + residual ----------------
__global__ __launch_bounds__(256) void up_kernel(
    const float* __restrict__ out2, const float* __restrict__ stats,
    const float* __restrict__ gamma, const float* __restrict__ beta,
    const float* __restrict__ mainf, float* __restrict__ out)
{
    int idx = blockIdx.x * 256 + threadIdx.x;   // < 4*64*128*128
    int j  = idx & 127;
    int i  = (idx >> 7) & 127;
    int co = (idx >> 14) & 63;            // uniform within a block
    int b  = idx >> 20;

    float mean = stats[co] * (1.0f / 16384.0f);
    float var  = stats[64 + co] * (1.0f / 16384.0f) - mean * mean;
    float inv  = rsqrtf(var + 1e-5f);
    float scale = gamma[co] * inv;
    float shift = beta[co] - mean * scale;

    // torch bilinear align_corners=False, 64 -> 128:
    // even i=2k: k==0 -> row[0]; else 0.25*row[k-1]+0.75*row[k]
    // odd  i=2k+1:      0.75*row[k]+0.25*row[min(k+1,63)]
    int ih = i >> 1, il = j >> 1;
    int k0, k1; float wi;
    if (i & 1)       { k0 = ih;     k1 = (ih < 63) ? ih + 1 : 63; wi = 0.25f; }
    else if (ih == 0){ k0 = 0;      k1 = 0;                       wi = 0.0f;  }
    else             { k0 = ih - 1; k1 = ih;                      wi = 0.75f; }
    int l0, l1; float wj;
    if (j & 1)       { l0 = il;     l1 = (il < 63) ? il + 1 : 63; wj = 0.25f; }
    else if (il == 0){ l0 = 0;      l1 = 0;                       wj = 0.0f;  }
    else             { l0 = il - 1; l1 = il;                      wj = 0.75f; }

    const float* p = out2 + ((size_t)((b << 6) | co) << 12);
    float v00 = p[(k0 << 6) | l0], v01 = p[(k0 << 6) | l1];
    float v10 = p[(k1 << 6) | l0], v11 = p[(k1 << 6) | l1];
    float top = v00 + wj * (v01 - v00);
    float bot = v10 + wj * (v11 - v10);
    float v = top + wi * (bot - top);
    out[idx] = fmaf(v, scale, shift) + mainf[idx];
}

extern "C" void kernel_launch(void* const* d_in, const int* in_sizes, int n_in,
                              void* d_out, int out_size, void* d_ws, size_t ws_size,
                              hipStream_t stream)
{
    const float* mainf = (const float*)d_in[0];
    const float* cross = (const float*)d_in[1];
    const float* g_w   = (const float*)d_in[2];
    const float* g_b   = (const float*)d_in[3];
    const float* th_w  = (const float*)d_in[4];
    const float* th_b  = (const float*)d_in[5];
    const float* ph_w  = (const float*)d_in[6];
    const float* ph_b  = (const float*)d_in[7];
    const float* w_w   = (const float*)d_in[8];
    const float* w_b   = (const float*)d_in[9];
    const float* gamma = (const float*)d_in[10];
    const float* beta  = (const float*)d_in[11];
    float* out = (float*)d_out;

    float* ws    = (float*)d_ws;
    float* Q     = ws;                 // 16384*32
    float* K     = Q + 524288;
    float* V     = K + 524288;
    float* O     = V + 524288;
    float* out2  = O + 524288;         // 4*64*4096
    float* stats = out2 + 1048576;     // 128

    qkv_kernel<<<256, 64, 0, stream>>>(cross, mainf, g_w, g_b, th_w, th_b,
                                       ph_w, ph_b, Q, K, V);
    attn_kernel<<<dim3(64, 4), 256, 0, stream>>>(Q, K, V, O);
    wconv_kernel<<<64, 256, 0, stream>>>(O, w_w, w_b, out2);
    stats_kernel<<<64, 256, 0, stream>>>(out2, stats);
    up_kernel<<<16384, 256, 0, stream>>>(out2, stats, gamma, beta, mainf, out);
}

// Round 2
// 189.354 us; speedup vs baseline: 3.3934x; 3.3934x over previous
//
#include <hip/hip_runtime.h>
#include <hip/hip_bf16.h>
#include <math.h>

// CrossLocal: B=4, C=64, CI=32, cross 64x64 (Nc=4096), main 128x128.
// R2: bf16 MFMA flash attention (no-max softmax, logits bounded).
// ws layout: Qb[bf16 4*4096*32] Kb[same] Vt[bf16 4*32*4096] O[f32 4*4096*32]
//            out2[f32 4*64*4096] stats[f32 128]

typedef __attribute__((ext_vector_type(8))) short bf16x8;
typedef __attribute__((ext_vector_type(4))) float f32x4;

static __device__ __forceinline__ unsigned short f2bf_bits(float x) {
    __hip_bfloat16 h = __float2bfloat16(x);
    return *(unsigned short*)&h;
}

// ---------------- Kernel 1: Q,K,V prep (bf16 out) ----------------
// thread = (pix, kind); kind: 0=Q (g), 1=K (theta), 2=V (phi on 2x2-pooled main)
__global__ __launch_bounds__(256) void qkv_kernel(
    const float* __restrict__ cross, const float* __restrict__ mainf,
    const float* __restrict__ g_w,  const float* __restrict__ g_b,
    const float* __restrict__ th_w, const float* __restrict__ th_b,
    const float* __restrict__ ph_w, const float* __restrict__ ph_b,
    __hip_bfloat16* __restrict__ Qb, __hip_bfloat16* __restrict__ Kb,
    __hip_bfloat16* __restrict__ Vt)
{
    int gid  = blockIdx.x * 256 + threadIdx.x;   // 0..49151
    int kind = gid >> 14;                        // uniform per block (64 blocks/kind)
    int pix  = gid & 16383;
    int b = pix >> 12, n = pix & 4095;

    const float* w  = (kind == 0) ? g_w : (kind == 1) ? th_w : ph_w;
    const float* bs = (kind == 0) ? g_b : (kind == 1) ? th_b : ph_b;

    float acc[32];
#pragma unroll
    for (int ci = 0; ci < 32; ++ci) acc[ci] = bs[ci];

    if (kind < 2) {
        const float* cp = cross + (size_t)(b * 64) * 4096 + n;
        for (int c = 0; c < 64; ++c) {
            float xc = cp[(size_t)c * 4096];
#pragma unroll
            for (int ci = 0; ci < 32; ++ci)
                acc[ci] = fmaf(w[(ci << 6) + c], xc, acc[ci]);
        }
        // pack 32 bf16 -> 4x uint4 stores
        unsigned int u[16];
#pragma unroll
        for (int i = 0; i < 16; ++i)
            u[i] = (unsigned int)f2bf_bits(acc[2 * i]) |
                   ((unsigned int)f2bf_bits(acc[2 * i + 1]) << 16);
        __hip_bfloat16* dst = ((kind == 0) ? Qb : Kb) + (size_t)pix * 32;
        uint4* d4 = (uint4*)dst;
#pragma unroll
        for (int r = 0; r < 4; ++r)
            d4[r] = make_uint4(u[4*r], u[4*r+1], u[4*r+2], u[4*r+3]);
    } else {
        int i = n >> 6, j = n & 63;
        const float* mp = mainf + (size_t)(b * 64) * 16384 + i * 256 + j * 2;
        for (int c = 0; c < 64; ++c) {
            const float* m = mp + (size_t)c * 16384;
            float xm = 0.25f * (m[0] + m[1] + m[128] + m[129]);
#pragma unroll
            for (int ci = 0; ci < 32; ++ci)
                acc[ci] = fmaf(w[(ci << 6) + c], xm, acc[ci]);
        }
        // Vt[b][ci][n] — per-ci coalesced b16 stores
#pragma unroll
        for (int ci = 0; ci < 32; ++ci)
            Vt[((size_t)((b << 5) | ci) << 12) + n] = __float2bfloat16(acc[ci]);
    }
}

// ---------------- Kernel 2: MFMA flash attention ----------------
// grid (256 qtiles of 16, 4 batch) x 256 thr. Wave w owns keys [w*1024,+1024).
// Per 32-key chunk: S = Q(16x32)·K^T via 2 mfma_16x16x32_bf16, exp (fp32),
// P->LDS->A-frag roundtrip, O += P·V via 2 mfma with B-frags from Vt.
__global__ __launch_bounds__(256) void attn_mfma(
    const __hip_bfloat16* __restrict__ Qb, const __hip_bfloat16* __restrict__ Kb,
    const __hip_bfloat16* __restrict__ Vt, float* __restrict__ O)
{
    __shared__ __align__(16) __hip_bfloat16 pbuf[4][16][40];  // per-wave P tile, pad 8
    __shared__ __align__(16) float redbuf[3][64][12];
    const int tid = threadIdx.x, lane = tid & 63, w = tid >> 6;
    const int lo = lane & 15, c = lane >> 4;
    const int b = blockIdx.y, qbase = blockIdx.x << 4;

    // A-frag: Q[qbase+lo][8c..8c+7]
    const bf16x8 aq = *(const bf16x8*)(Qb + (((size_t)(b << 12) + qbase + lo) << 5) + (c << 3));

    const __hip_bfloat16* Kbb = Kb + ((size_t)(b << 12) << 5);
    const __hip_bfloat16* Vbb = Vt + ((size_t)(b << 5) << 12);

    f32x4 acc0 = {0.f, 0.f, 0.f, 0.f}, acc1 = {0.f, 0.f, 0.f, 0.f};
    float den[4] = {0.f, 0.f, 0.f, 0.f};

    const int kq = w << 10;
    // B-frag loaders: K[key=k+lo][ci=8c..+7], V[key=k+8c..+7][ci=lo(+16)]
#define LDK(k)      (*(const bf16x8*)(Kbb + ((size_t)((k) + lo) << 5) + (c << 3)))
#define LDV(k, cio) (*(const bf16x8*)(Vbb + ((size_t)(lo + (cio)) << 12) + (k) + (c << 3)))

    bf16x8 bk0 = LDK(kq), bk1 = LDK(kq + 16);
    bf16x8 bv0 = LDV(kq, 0), bv1 = LDV(kq, 16);

    for (int ch = 0; ch < 32; ++ch) {
        const int kn = kq | (((ch + 1) & 31) << 5);   // next chunk (wrap reload on last)
        bf16x8 nk0 = LDK(kn), nk1 = LDK(kn + 16);
        bf16x8 nv0 = LDV(kn, 0), nv1 = LDV(kn, 16);

        const f32x4 z = {0.f, 0.f, 0.f, 0.f};
        f32x4 s0 = __builtin_amdgcn_mfma_f32_16x16x32_bf16(aq, bk0, z, 0, 0, 0);
        f32x4 s1 = __builtin_amdgcn_mfma_f32_16x16x32_bf16(aq, bk1, z, 0, 0, 0);

        // C-layout: lane holds S[q=4c+r][key = kq+32ch + lo (+16)]
#pragma unroll
        for (int r = 0; r < 4; ++r) {
            float p0 = __expf(s0[r]);
            float p1 = __expf(s1[r]);
            den[r] += p0 + p1;
            pbuf[w][(c << 2) | r][lo]      = __float2bfloat16(p0);
            pbuf[w][(c << 2) | r][16 + lo] = __float2bfloat16(p1);
        }
        // A-frag of P: P[q=lo][k=8c..8c+7] (same-wave LDS, in-order DS pipe)
        bf16x8 ap = *(const bf16x8*)&pbuf[w][lo][c << 3];
        acc0 = __builtin_amdgcn_mfma_f32_16x16x32_bf16(ap, bv0, acc0, 0, 0, 0);
        acc1 = __builtin_amdgcn_mfma_f32_16x16x32_bf16(ap, bv1, acc1, 0, 0, 0);

        bk0 = nk0; bk1 = nk1; bv0 = nv0; bv1 = nv1;
    }
#undef LDK
#undef LDV

    // cross-wave combine (partials are purely additive)
    if (w) {
        f32x4* rb = (f32x4*)&redbuf[w - 1][lane][0];
        rb[0] = acc0; rb[1] = acc1;
        f32x4 dv = {den[0], den[1], den[2], den[3]};
        rb[2] = dv;
    }
    __syncthreads();
    if (w == 0) {
#pragma unroll
        for (int ww = 0; ww < 3; ++ww) {
            const f32x4* rb = (const f32x4*)&redbuf[ww][lane][0];
            f32x4 a0 = rb[0], a1 = rb[1], dv = rb[2];
            acc0 += a0; acc1 += a1;
#pragma unroll
            for (int r = 0; r < 4; ++r) den[r] += dv[r];
        }
        // row sums: reduce den over the 16 lanes sharing c (bits 0..3)
#pragma unroll
        for (int off = 1; off < 16; off <<= 1) {
#pragma unroll
            for (int r = 0; r < 4; ++r) den[r] += __shfl_xor(den[r], off);
        }
        float* Orow = O + (((size_t)(b << 12) + qbase + (c << 2)) << 5) + lo;
#pragma unroll
        for (int r = 0; r < 4; ++r) {
            float inv = 1.0f / den[r];
            Orow[(size_t)(r << 5)]      = acc0[r] * inv;
            Orow[(size_t)(r << 5) + 16] = acc1[r] * inv;
        }
    }
}

// ---------------- Kernel 3a: W 1x1 conv ----------------
// block: 64 pix x 4 co-groups of 16; grid 256
__global__ __launch_bounds__(256) void wconv_kernel(
    const float* __restrict__ O, const float* __restrict__ w_w,
    const float* __restrict__ w_b, float* __restrict__ out2)
{
    int pixl = threadIdx.x & 63, cog = threadIdx.x >> 6;
    int pix = blockIdx.x * 64 + pixl;
    int b = pix >> 12, n = pix & 4095;
    float o[32];
    const float4* Op = (const float4*)(O + (size_t)pix * 32);
#pragma unroll
    for (int r = 0; r < 8; ++r) {
        float4 v4 = Op[r];
        o[4*r] = v4.x; o[4*r+1] = v4.y; o[4*r+2] = v4.z; o[4*r+3] = v4.w;
    }
#pragma unroll
    for (int cl = 0; cl < 16; ++cl) {
        int co = (cog << 4) | cl;
        float acc = w_b[co];
#pragma unroll
        for (int ci = 0; ci < 32; ++ci)
            acc = fmaf(w_w[(co << 5) + ci], o[ci], acc);
        out2[((size_t)((b << 6) | co) << 12) + n] = acc;
    }
}

// ---------------- Kernel 3b: BN batch statistics ----------------
__global__ __launch_bounds__(256) void stats_kernel(
    const float* __restrict__ out2, float* __restrict__ stats)
{
    int co = blockIdx.x, t = threadIdx.x;
    float s = 0.f, s2 = 0.f;
    for (int b = 0; b < 4; ++b) {
        const float* p = out2 + ((size_t)((b << 6) | co) << 12);
#pragma unroll
        for (int ii = 0; ii < 16; ++ii) {
            float v = p[(ii << 8) | t];
            s += v; s2 = fmaf(v, v, s2);
        }
    }
    __shared__ float rs[256], rs2[256];
    rs[t] = s; rs2[t] = s2;
    __syncthreads();
    for (int off = 128; off > 0; off >>= 1) {
        if (t < off) { rs[t] += rs[t + off]; rs2[t] += rs2[t + off]; }
        __syncthreads();
    }
    if (t == 0) { stats[co] = rs[0]; stats[64 + co] = rs2[0]; }
}

// ---------------- Kernel 4: BN + bilinear 64->128 + residual ----------------
__global__ __launch_bounds__(256) void up_kernel(
    const float* __restrict__ out2, const float* __restrict__ stats,
    const float* __restrict__ gamma, const float* __restrict__ beta,
    const float* __restrict__ mainf, float* __restrict__ out)
{
    int idx = blockIdx.x * 256 + threadIdx.x;   // < 4*64*128*128
    int j  = idx & 127;
    int i  = (idx >> 7) & 127;
    int co = (idx >> 14) & 63;            // uniform within a block
    int b  = idx >> 20;

    float mean = stats[co] * (1.0f / 16384.0f);
    float var  = stats[64 + co] * (1.0f / 16384.0f) - mean * mean;
    float inv  = rsqrtf(var + 1e-5f);
    float scale = gamma[co] * inv;
    float shift = beta[co] - mean * scale;

    int ih = i >> 1, il = j >> 1;
    int k0, k1; float wi;
    if (i & 1)       { k0 = ih;     k1 = (ih < 63) ? ih + 1 : 63; wi = 0.25f; }
    else if (ih == 0){ k0 = 0;      k1 = 0;                       wi = 0.0f;  }
    else             { k0 = ih - 1; k1 = ih;                      wi = 0.75f; }
    int l0, l1; float wj;
    if (j & 1)       { l0 = il;     l1 = (il < 63) ? il + 1 : 63; wj = 0.25f; }
    else if (il == 0){ l0 = 0;      l1 = 0;                       wj = 0.0f;  }
    else             { l0 = il - 1; l1 = il;                      wj = 0.75f; }

    const float* p = out2 + ((size_t)((b << 6) | co) << 12);
    float v00 = p[(k0 << 6) | l0], v01 = p[(k0 << 6) | l1];
    float v10 = p[(k1 << 6) | l0], v11 = p[(k1 << 6) | l1];
    float top = v00 + wj * (v01 - v00);
    float bot = v10 + wj * (v11 - v10);
    float v = top + wi * (bot - top);
    out[idx] = fmaf(v, scale, shift) + mainf[idx];
}

extern "C" void kernel_launch(void* const* d_in, const int* in_sizes, int n_in,
                              void* d_out, int out_size, void* d_ws, size_t ws_size,
                              hipStream_t stream)
{
    const float* mainf = (const float*)d_in[0];
    const float* cross = (const float*)d_in[1];
    const float* g_w   = (const float*)d_in[2];
    const float* g_b   = (const float*)d_in[3];
    const float* th_w  = (const float*)d_in[4];
    const float* th_b  = (const float*)d_in[5];
    const float* ph_w  = (const float*)d_in[6];
    const float* ph_b  = (const float*)d_in[7];
    const float* w_w   = (const float*)d_in[8];
    const float* w_b   = (const float*)d_in[9];
    const float* gamma = (const float*)d_in[10];
    const float* beta  = (const float*)d_in[11];
    float* out = (float*)d_out;

    __hip_bfloat16* Qb = (__hip_bfloat16*)d_ws;     // 4*4096*32
    __hip_bfloat16* Kb = Qb + 524288;
    __hip_bfloat16* Vt = Kb + 524288;               // [b][ci][4096]
    float* O     = (float*)(Vt + 524288);           // 4*4096*32
    float* out2  = O + 524288;                      // 4*64*4096
    float* stats = out2 + 1048576;                  // 128

    qkv_kernel<<<192, 256, 0, stream>>>(cross, mainf, g_w, g_b, th_w, th_b,
                                        ph_w, ph_b, Qb, Kb, Vt);
    attn_mfma<<<dim3(256, 4), 256, 0, stream>>>(Qb, Kb, Vt, O);
    wconv_kernel<<<256, 256, 0, stream>>>(O, w_w, w_b, out2);
    stats_kernel<<<64, 256, 0, stream>>>(out2, stats);
    up_kernel<<<16384, 256, 0, stream>>>(out2, stats, gamma, beta, mainf, out);
}

// Round 3
// 182.207 us; speedup vs baseline: 3.5265x; 1.0392x over previous
//
#include <hip/hip_runtime.h>
#include <hip/hip_bf16.h>

// CrossLocal: B=4, C=64, CI=32, cross 64x64 (Nc=4096), main 128x128.
// R3: pipelined bf16 MFMA flash attention + exp2 trick + fused W-conv epilogue.
// ws: Qb[bf16 4*4096*32] Kb[same] Vt[bf16 4*32*4096] out2[f32 4*64*4096] stats[128]

typedef __attribute__((ext_vector_type(8))) short bf16x8;
typedef __attribute__((ext_vector_type(4))) float f32x4;

#define LOG2E 1.4426950408889634f

static __device__ __forceinline__ unsigned short f2bf_bits(float x) {
    __hip_bfloat16 h = __float2bfloat16(x);
    return *(unsigned short*)&h;
}

// ---------------- Kernel 1: Q,K,V prep (bf16 out) ----------------
// kind: 0=Q (g, pre-scaled by log2e), 1=K (theta), 2=V (phi on 2x2-pooled main)
__global__ __launch_bounds__(256) void qkv_kernel(
    const float* __restrict__ cross, const float* __restrict__ mainf,
    const float* __restrict__ g_w,  const float* __restrict__ g_b,
    const float* __restrict__ th_w, const float* __restrict__ th_b,
    const float* __restrict__ ph_w, const float* __restrict__ ph_b,
    __hip_bfloat16* __restrict__ Qb, __hip_bfloat16* __restrict__ Kb,
    __hip_bfloat16* __restrict__ Vt)
{
    int gid  = blockIdx.x * 256 + threadIdx.x;   // 0..49151
    int kind = gid >> 14;                        // uniform per block
    int pix  = gid & 16383;
    int b = pix >> 12, n = pix & 4095;

    const float* w  = (kind == 0) ? g_w : (kind == 1) ? th_w : ph_w;
    const float* bs = (kind == 0) ? g_b : (kind == 1) ? th_b : ph_b;

    float acc[32];
#pragma unroll
    for (int ci = 0; ci < 32; ++ci) acc[ci] = bs[ci];

    if (kind < 2) {
        const float* cp = cross + (size_t)(b * 64) * 4096 + n;
        for (int c = 0; c < 64; ++c) {
            float xc = cp[(size_t)c * 4096];
#pragma unroll
            for (int ci = 0; ci < 32; ++ci)
                acc[ci] = fmaf(w[(ci << 6) + c], xc, acc[ci]);
        }
        if (kind == 0) {
#pragma unroll
            for (int ci = 0; ci < 32; ++ci) acc[ci] *= LOG2E;
        }
        unsigned int u[16];
#pragma unroll
        for (int i = 0; i < 16; ++i)
            u[i] = (unsigned int)f2bf_bits(acc[2 * i]) |
                   ((unsigned int)f2bf_bits(acc[2 * i + 1]) << 16);
        __hip_bfloat16* dst = ((kind == 0) ? Qb : Kb) + (size_t)pix * 32;
        uint4* d4 = (uint4*)dst;
#pragma unroll
        for (int r = 0; r < 4; ++r)
            d4[r] = make_uint4(u[4*r], u[4*r+1], u[4*r+2], u[4*r+3]);
    } else {
        int i = n >> 6, j = n & 63;
        const float* mp = mainf + (size_t)(b * 64) * 16384 + i * 256 + j * 2;
        for (int c = 0; c < 64; ++c) {
            const float* m = mp + (size_t)c * 16384;
            float xm = 0.25f * (m[0] + m[1] + m[128] + m[129]);
#pragma unroll
            for (int ci = 0; ci < 32; ++ci)
                acc[ci] = fmaf(w[(ci << 6) + c], xm, acc[ci]);
        }
#pragma unroll
        for (int ci = 0; ci < 32; ++ci)
            Vt[((size_t)((b << 5) | ci) << 12) + n] = __float2bfloat16(acc[ci]);
    }
}

// ---------------- Kernel 2: pipelined MFMA flash attention + W conv ----------------
// grid (256 qtiles of 16, 4 batch) x 256 thr. Wave w owns keys [w*1024,+1024).
// Pipeline: iter ch computes S(ch)+exp->pbuf[ch&1], and PV(ch-1) from
// pbuf[(ch-1)&1] (ds_read issued before this iter's writes -> latency hidden).
__global__ __launch_bounds__(256) void attn_mfma(
    const __hip_bfloat16* __restrict__ Qb, const __hip_bfloat16* __restrict__ Kb,
    const __hip_bfloat16* __restrict__ Vt, const float* __restrict__ w_w,
    const float* __restrict__ w_b, float* __restrict__ out2)
{
    __shared__ __align__(16) __hip_bfloat16 pbuf[4][2][16][44]; // stride 44: conflict-free writes
    __shared__ __align__(16) float redbuf[3][64][12];
    __shared__ __align__(16) float obuf[16][36];                // O tile, 16B-aligned rows
    const int tid = threadIdx.x, lane = tid & 63, w = tid >> 6;
    const int lo = lane & 15, c = lane >> 4;
    const int b = blockIdx.y, qbase = blockIdx.x << 4;

    const bf16x8 aq = *(const bf16x8*)(Qb + (((size_t)(b << 12) + qbase + lo) << 5) + (c << 3));
    const __hip_bfloat16* Kbb = Kb + ((size_t)(b << 12) << 5);
    const __hip_bfloat16* Vbb = Vt + ((size_t)(b << 5) << 12);

    f32x4 acc0 = {0.f,0.f,0.f,0.f}, acc1 = {0.f,0.f,0.f,0.f};
    float den[4] = {0.f,0.f,0.f,0.f};
    const f32x4 z = {0.f,0.f,0.f,0.f};
    const int kq = w << 10;
#define LDK(k)      (*(const bf16x8*)(Kbb + ((size_t)((k) + lo) << 5) + (c << 3)))
#define LDV(k, cio) (*(const bf16x8*)(Vbb + ((size_t)(lo + (cio)) << 12) + (k) + (c << 3)))

    bf16x8 k0a = LDK(kq), k1a = LDK(kq + 16);
    bf16x8 v0a = LDV(kq, 0), v1a = LDV(kq, 16);

    // ---- chunk 0: S phase only ----
    {
        f32x4 s0 = __builtin_amdgcn_mfma_f32_16x16x32_bf16(aq, k0a, z, 0, 0, 0);
        f32x4 s1 = __builtin_amdgcn_mfma_f32_16x16x32_bf16(aq, k1a, z, 0, 0, 0);
#pragma unroll
        for (int r = 0; r < 4; ++r) {
            float p0 = __builtin_amdgcn_exp2f(s0[r]);
            float p1 = __builtin_amdgcn_exp2f(s1[r]);
            den[r] += p0 + p1;
            pbuf[w][0][(c << 2) | r][lo]      = __float2bfloat16(p0);
            pbuf[w][0][(c << 2) | r][16 + lo] = __float2bfloat16(p1);
        }
    }
    bf16x8 pv0 = v0a, pv1 = v1a;
    k0a = LDK(kq + 32); k1a = LDK(kq + 48);
    v0a = LDV(kq + 32, 0); v1a = LDV(kq + 32, 16);

#pragma unroll 2
    for (int ch = 1; ch < 32; ++ch) {
        const int kn = kq | (((ch + 1) & 31) << 5);
        bf16x8 nk0 = LDK(kn), nk1 = LDK(kn + 16);
        bf16x8 nv0 = LDV(kn, 0), nv1 = LDV(kn, 16);

        // PV of chunk ch-1 (read issued before this chunk's writes)
        bf16x8 ap = *(const bf16x8*)&pbuf[w][(ch - 1) & 1][lo][c << 3];
        acc0 = __builtin_amdgcn_mfma_f32_16x16x32_bf16(ap, pv0, acc0, 0, 0, 0);
        acc1 = __builtin_amdgcn_mfma_f32_16x16x32_bf16(ap, pv1, acc1, 0, 0, 0);

        // S of chunk ch
        f32x4 s0 = __builtin_amdgcn_mfma_f32_16x16x32_bf16(aq, k0a, z, 0, 0, 0);
        f32x4 s1 = __builtin_amdgcn_mfma_f32_16x16x32_bf16(aq, k1a, z, 0, 0, 0);
#pragma unroll
        for (int r = 0; r < 4; ++r) {
            float p0 = __builtin_amdgcn_exp2f(s0[r]);
            float p1 = __builtin_amdgcn_exp2f(s1[r]);
            den[r] += p0 + p1;
            pbuf[w][ch & 1][(c << 2) | r][lo]      = __float2bfloat16(p0);
            pbuf[w][ch & 1][(c << 2) | r][16 + lo] = __float2bfloat16(p1);
        }
        pv0 = v0a; pv1 = v1a;
        k0a = nk0; k1a = nk1; v0a = nv0; v1a = nv1;
    }
    {   // PV of chunk 31
        bf16x8 ap = *(const bf16x8*)&pbuf[w][1][lo][c << 3];
        acc0 = __builtin_amdgcn_mfma_f32_16x16x32_bf16(ap, pv0, acc0, 0, 0, 0);
        acc1 = __builtin_amdgcn_mfma_f32_16x16x32_bf16(ap, pv1, acc1, 0, 0, 0);
    }
#undef LDK
#undef LDV

    // ---- cross-wave combine ----
    if (w) {
        f32x4* rb = (f32x4*)&redbuf[w - 1][lane][0];
        rb[0] = acc0; rb[1] = acc1;
        f32x4 dv = {den[0], den[1], den[2], den[3]};
        rb[2] = dv;
    }
    __syncthreads();
    if (w == 0) {
#pragma unroll
        for (int ww = 0; ww < 3; ++ww) {
            const f32x4* rb = (const f32x4*)&redbuf[ww][lane][0];
            f32x4 a0 = rb[0], a1 = rb[1], dv = rb[2];
            acc0 += a0; acc1 += a1;
#pragma unroll
            for (int r = 0; r < 4; ++r) den[r] += dv[r];
        }
#pragma unroll
        for (int off = 1; off < 16; off <<= 1) {
#pragma unroll
            for (int r = 0; r < 4; ++r) den[r] += __shfl_xor(den[r], off);
        }
#pragma unroll
        for (int r = 0; r < 4; ++r) {
            float inv = 1.0f / den[r];
            obuf[(c << 2) | r][lo]      = acc0[r] * inv;
            obuf[(c << 2) | r][16 + lo] = acc1[r] * inv;
        }
    }
    __syncthreads();

    // ---- fused W 1x1 conv: out2[b][co][qbase+q] = w_b[co] + sum_ci O[q][ci] w_w[co][ci]
    const int q = tid & 15, cog = tid >> 4;
    float ov[32];
    const float4* orow = (const float4*)&obuf[q][0];
#pragma unroll
    for (int k4 = 0; k4 < 8; ++k4) {
        float4 t = orow[k4];
        ov[4*k4] = t.x; ov[4*k4+1] = t.y; ov[4*k4+2] = t.z; ov[4*k4+3] = t.w;
    }
    float* dstbase = out2 + (((size_t)(b << 6)) << 12) + qbase + q;
#pragma unroll
    for (int kk = 0; kk < 4; ++kk) {
        int co = (kk << 4) | cog;
        const float4* wr = (const float4*)&w_w[co << 5];
        float acc = w_b[co];
#pragma unroll
        for (int k4 = 0; k4 < 8; ++k4) {
            float4 t = wr[k4];
            acc = fmaf(t.x, ov[4*k4],   acc);
            acc = fmaf(t.y, ov[4*k4+1], acc);
            acc = fmaf(t.z, ov[4*k4+2], acc);
            acc = fmaf(t.w, ov[4*k4+3], acc);
        }
        dstbase[(size_t)co << 12] = acc;
    }
}

// ---------------- Kernel 3: BN batch statistics ----------------
__global__ __launch_bounds__(256) void stats_kernel(
    const float* __restrict__ out2, float* __restrict__ stats)
{
    int co = blockIdx.x, t = threadIdx.x;
    float s = 0.f, s2 = 0.f;
    for (int b = 0; b < 4; ++b) {
        const float* p = out2 + ((size_t)((b << 6) | co) << 12);
#pragma unroll
        for (int ii = 0; ii < 16; ++ii) {
            float v = p[(ii << 8) | t];
            s += v; s2 = fmaf(v, v, s2);
        }
    }
    __shared__ float rs[256], rs2[256];
    rs[t] = s; rs2[t] = s2;
    __syncthreads();
    for (int off = 128; off > 0; off >>= 1) {
        if (t < off) { rs[t] += rs[t + off]; rs2[t] += rs2[t + off]; }
        __syncthreads();
    }
    if (t == 0) { stats[co] = rs[0]; stats[64 + co] = rs2[0]; }
}

// ---------------- Kernel 4: BN + bilinear 64->128 + residual ----------------
__global__ __launch_bounds__(256) void up_kernel(
    const float* __restrict__ out2, const float* __restrict__ stats,
    const float* __restrict__ gamma, const float* __restrict__ beta,
    const float* __restrict__ mainf, float* __restrict__ out)
{
    int idx = blockIdx.x * 256 + threadIdx.x;   // < 4*64*128*128
    int j  = idx & 127;
    int i  = (idx >> 7) & 127;
    int co = (idx >> 14) & 63;            // uniform within a block
    int b  = idx >> 20;

    float mean = stats[co] * (1.0f / 16384.0f);
    float var  = stats[64 + co] * (1.0f / 16384.0f) - mean * mean;
    float inv  = rsqrtf(var + 1e-5f);
    float scale = gamma[co] * inv;
    float shift = beta[co] - mean * scale;

    int ih = i >> 1, il = j >> 1;
    int k0, k1; float wi;
    if (i & 1)       { k0 = ih;     k1 = (ih < 63) ? ih + 1 : 63; wi = 0.25f; }
    else if (ih == 0){ k0 = 0;      k1 = 0;                       wi = 0.0f;  }
    else             { k0 = ih - 1; k1 = ih;                      wi = 0.75f; }
    int l0, l1; float wj;
    if (j & 1)       { l0 = il;     l1 = (il < 63) ? il + 1 : 63; wj = 0.25f; }
    else if (il == 0){ l0 = 0;      l1 = 0;                       wj = 0.0f;  }
    else             { l0 = il - 1; l1 = il;                      wj = 0.75f; }

    const float* p = out2 + ((size_t)((b << 6) | co) << 12);
    float v00 = p[(k0 << 6) | l0], v01 = p[(k0 << 6) | l1];
    float v10 = p[(k1 << 6) | l0], v11 = p[(k1 << 6) | l1];
    float top = v00 + wj * (v01 - v00);
    float bot = v10 + wj * (v11 - v10);
    float v = top + wi * (bot - top);
    out[idx] = fmaf(v, scale, shift) + mainf[idx];
}

extern "C" void kernel_launch(void* const* d_in, const int* in_sizes, int n_in,
                              void* d_out, int out_size, void* d_ws, size_t ws_size,
                              hipStream_t stream)
{
    const float* mainf = (const float*)d_in[0];
    const float* cross = (const float*)d_in[1];
    const float* g_w   = (const float*)d_in[2];
    const float* g_b   = (const float*)d_in[3];
    const float* th_w  = (const float*)d_in[4];
    const float* th_b  = (const float*)d_in[5];
    const float* ph_w  = (const float*)d_in[6];
    const float* ph_b  = (const float*)d_in[7];
    const float* w_w   = (const float*)d_in[8];
    const float* w_b   = (const float*)d_in[9];
    const float* gamma = (const float*)d_in[10];
    const float* beta  = (const float*)d_in[11];
    float* out = (float*)d_out;

    __hip_bfloat16* Qb = (__hip_bfloat16*)d_ws;     // 4*4096*32
    __hip_bfloat16* Kb = Qb + 524288;
    __hip_bfloat16* Vt = Kb + 524288;               // [b][ci][4096]
    float* out2  = (float*)(Vt + 524288);           // 4*64*4096
    float* stats = out2 + 1048576;                  // 128

    qkv_kernel<<<192, 256, 0, stream>>>(cross, mainf, g_w, g_b, th_w, th_b,
                                        ph_w, ph_b, Qb, Kb, Vt);
    attn_mfma<<<dim3(256, 4), 256, 0, stream>>>(Qb, Kb, Vt, w_w, w_b, out2);
    stats_kernel<<<64, 256, 0, stream>>>(out2, stats);
    up_kernel<<<16384, 256, 0, stream>>>(out2, stats, gamma, beta, mainf, out);
}